// Round 3
// baseline (99.247 us; speedup 1.0000x reference)
//
#include <hip/hip_runtime.h>

// out[b,o,ds] = sum_i x[b,i] * peso[o,i,ds] for i where mask[o,i]==1
// B=256, IN=1024, OUT=512, DS=128, ~10% of (o,i) kept (mask values exactly {0,1}).
//
// spmm v2: block=(o, 64-b tile), 4 waves; wave -> 16 b rows, lane -> float2 of ds.
// x slabs staged in LDS in chunks of 64 i-rows -> inner loop reads x via
// uniform-address ds_read_b128 broadcasts instead of scalar-L2 loads.

#define B_   256
#define IN_  1024
#define OUT_ 512
#define DS_  128
#define CH   64   // i-rows staged per chunk (16 KiB LDS)

// ws layout:
//   [0, 1 MiB)              xT  float[IN_][B_]
//   [1 MiB, +2 KiB)         cnt int[OUT_]
//   [1 MiB + 4 KiB, +2 MiB) idx int[OUT_][IN_]

__global__ __launch_bounds__(256) void transpose_x(const float* __restrict__ x,
                                                   float* __restrict__ xT) {
    __shared__ float tile[64][65];
    int t  = threadIdx.x;
    int c  = t & 63;
    int r0 = t >> 6;
    int i0 = (blockIdx.x & 15) * 64;
    int b0 = (blockIdx.x >> 4) * 64;
#pragma unroll
    for (int k = 0; k < 16; ++k) {
        int r = r0 + k * 4;
        tile[r][c] = x[(size_t)(b0 + r) * IN_ + i0 + c];
    }
    __syncthreads();
#pragma unroll
    for (int k = 0; k < 16; ++k) {
        int r = r0 + k * 4;
        xT[(size_t)(i0 + r) * B_ + b0 + c] = tile[c][r];
    }
}

__global__ __launch_bounds__(256) void build_idx(const float* __restrict__ mask,
                                                 int* __restrict__ cnt,
                                                 int* __restrict__ idx) {
    int o    = blockIdx.x;
    int t    = threadIdx.x;
    int lane = t & 63;
    int wv   = t >> 6;
    const float* mrow = mask + (size_t)o * IN_;

    int loc[4];
    int c = 0;
    int ibase = t * 4;
#pragma unroll
    for (int k = 0; k < 4; ++k) {
        if (mrow[ibase + k] != 0.0f) loc[c++] = ibase + k;
    }
    int v = c;
#pragma unroll
    for (int off = 1; off < 64; off <<= 1) {
        int u = __shfl_up(v, off, 64);
        if (lane >= off) v += u;
    }
    __shared__ int wsum[4];
    if (lane == 63) wsum[wv] = v;
    __syncthreads();
    int base = 0;
    for (int w = 0; w < wv; ++w) base += wsum[w];
    int excl = base + v - c;

    int* orow = idx + (size_t)o * IN_;
    for (int k = 0; k < c; ++k) orow[excl + k] = loc[k];
    if (t == 255) cnt[o] = base + v;
}

__global__ __launch_bounds__(256, 6) void spmm_kernel(const float* __restrict__ xT,
                                                      const float* __restrict__ peso,
                                                      const int* __restrict__ cnt,
                                                      const int* __restrict__ idx,
                                                      float* __restrict__ out) {
    __shared__ float xs[CH * 64];

    int bid  = blockIdx.x;
    int o    = bid & (OUT_ - 1);          // all 4 b-tiles of an o land on one XCD
    int bt   = bid >> 9;                  // 0..3
    int t    = threadIdx.x;
    int lane = t & 63;
    int wv   = __builtin_amdgcn_readfirstlane(t >> 6);
    int b0   = bt * 64;                   // block's b base
    int bw   = wv * 16;                   // wave's b offset within block

    float2 acc[16];
#pragma unroll
    for (int k = 0; k < 16; ++k) acc[k] = make_float2(0.0f, 0.0f);

    int n = cnt[o];
    const int*    irow  = idx + (size_t)o * IN_;
    const float2* wlane = (const float2*)(peso + (size_t)o * IN_ * DS_) + lane;

    for (int c0 = 0; c0 < n; c0 += CH) {
        int cn = min(CH, n - c0);
        __syncthreads();
        for (int f = t; f < (cn << 6); f += 256) {
            int r  = f >> 6;
            int cc = f & 63;
            xs[f] = xT[(size_t)irow[c0 + r] * B_ + b0 + cc];   // coalesced 256B/row
        }
        __syncthreads();
#pragma unroll 2
        for (int j = 0; j < cn; ++j) {
            int i = __builtin_amdgcn_readfirstlane(irow[c0 + j]);
            float2 w = wlane[(size_t)i * (DS_ / 2)];           // coalesced 512B/wave
            const float4* xv = (const float4*)&xs[(j << 6) + bw]; // uniform -> broadcast
            float4 xa = xv[0], xb = xv[1], xc = xv[2], xd = xv[3];
#pragma unroll
            for (int k = 0; k < 4; ++k) {
                float xk = (k == 0) ? xa.x : (k == 1) ? xb.x : (k == 2) ? xc.x : xd.x;
            }
            // unrolled FMAs (16 b x 2 ds)
            acc[0].x  = fmaf(xa.x, w.x, acc[0].x);  acc[0].y  = fmaf(xa.x, w.y, acc[0].y);
            acc[1].x  = fmaf(xa.y, w.x, acc[1].x);  acc[1].y  = fmaf(xa.y, w.y, acc[1].y);
            acc[2].x  = fmaf(xa.z, w.x, acc[2].x);  acc[2].y  = fmaf(xa.z, w.y, acc[2].y);
            acc[3].x  = fmaf(xa.w, w.x, acc[3].x);  acc[3].y  = fmaf(xa.w, w.y, acc[3].y);
            acc[4].x  = fmaf(xb.x, w.x, acc[4].x);  acc[4].y  = fmaf(xb.x, w.y, acc[4].y);
            acc[5].x  = fmaf(xb.y, w.x, acc[5].x);  acc[5].y  = fmaf(xb.y, w.y, acc[5].y);
            acc[6].x  = fmaf(xb.z, w.x, acc[6].x);  acc[6].y  = fmaf(xb.z, w.y, acc[6].y);
            acc[7].x  = fmaf(xb.w, w.x, acc[7].x);  acc[7].y  = fmaf(xb.w, w.y, acc[7].y);
            acc[8].x  = fmaf(xc.x, w.x, acc[8].x);  acc[8].y  = fmaf(xc.x, w.y, acc[8].y);
            acc[9].x  = fmaf(xc.y, w.x, acc[9].x);  acc[9].y  = fmaf(xc.y, w.y, acc[9].y);
            acc[10].x = fmaf(xc.z, w.x, acc[10].x); acc[10].y = fmaf(xc.z, w.y, acc[10].y);
            acc[11].x = fmaf(xc.w, w.x, acc[11].x); acc[11].y = fmaf(xc.w, w.y, acc[11].y);
            acc[12].x = fmaf(xd.x, w.x, acc[12].x); acc[12].y = fmaf(xd.x, w.y, acc[12].y);
            acc[13].x = fmaf(xd.y, w.x, acc[13].x); acc[13].y = fmaf(xd.y, w.y, acc[13].y);
            acc[14].x = fmaf(xd.z, w.x, acc[14].x); acc[14].y = fmaf(xd.z, w.y, acc[14].y);
            acc[15].x = fmaf(xd.w, w.x, acc[15].x); acc[15].y = fmaf(xd.w, w.y, acc[15].y);
        }
    }

    float* obase = out + (size_t)(b0 + bw) * (OUT_ * DS_) + o * DS_ + 2 * lane;
#pragma unroll
    for (int k = 0; k < 16; ++k) {
        *(float2*)(obase + (size_t)k * (OUT_ * DS_)) = acc[k];  // 512B/wave contiguous
    }
}

extern "C" void kernel_launch(void* const* d_in, const int* in_sizes, int n_in,
                              void* d_out, int out_size, void* d_ws, size_t ws_size,
                              hipStream_t stream) {
    const float* x    = (const float*)d_in[0];
    const float* peso = (const float*)d_in[1];
    const float* mask = (const float*)d_in[2];
    float* out = (float*)d_out;

    char* ws = (char*)d_ws;
    float* xT  = (float*)ws;
    int*   cnt = (int*)(ws + (1 << 20));
    int*   idx = (int*)(ws + (1 << 20) + 4096);

    transpose_x<<<64, 256, 0, stream>>>(x, xT);
    build_idx<<<OUT_, 256, 0, stream>>>(mask, cnt, idx);
    spmm_kernel<<<OUT_ * 4, 256, 0, stream>>>(xT, peso, cnt, idx, out);
}

// Round 5
// 71.052 us; speedup vs baseline: 1.3968x; 1.3968x over previous
//
#include <hip/hip_runtime.h>

// out[b,o,ds] = sum_i x[b,i] * peso[o,i,ds] for i where mask[o,i]==1
// B=256, IN=1024, OUT=512, DS=128, ~10% of (o,i) kept (mask values exactly {0,1}).
//
// spmm v3 (= R1 dataflow + LDS-cached index list + explicit depth-2 pipeline):
// block=(o, 64-b tile), 4 waves; wave -> 16 b rows, lane -> float2 of ds.
// Indices read from LDS (uniform-addr broadcast); x slab is a wave-uniform
// 64B scalar load; w is one coalesced 512B VMEM load. Next iter's loads are
// issued before this iter's 32 FMAs.

#define B_   256
#define IN_  1024
#define OUT_ 512
#define DS_  128

typedef float f16v __attribute__((ext_vector_type(16)));

// ws layout:
//   [0, 1 MiB)              xT  float[IN_][B_]
//   [1 MiB, +2 KiB)         cnt int[OUT_]
//   [1 MiB + 4 KiB, +2 MiB) idx int[OUT_][IN_]

__global__ __launch_bounds__(256) void transpose_x(const float* __restrict__ x,
                                                   float* __restrict__ xT) {
    __shared__ float tile[64][65];
    int t  = threadIdx.x;
    int c  = t & 63;
    int r0 = t >> 6;
    int i0 = (blockIdx.x & 15) * 64;
    int b0 = (blockIdx.x >> 4) * 64;
#pragma unroll
    for (int k = 0; k < 16; ++k) {
        int r = r0 + k * 4;
        tile[r][c] = x[(size_t)(b0 + r) * IN_ + i0 + c];
    }
    __syncthreads();
#pragma unroll
    for (int k = 0; k < 16; ++k) {
        int r = r0 + k * 4;
        xT[(size_t)(i0 + r) * B_ + b0 + c] = tile[c][r];
    }
}

__global__ __launch_bounds__(256) void build_idx(const float* __restrict__ mask,
                                                 int* __restrict__ cnt,
                                                 int* __restrict__ idx) {
    int o    = blockIdx.x;
    int t    = threadIdx.x;
    int lane = t & 63;
    int wv   = t >> 6;
    const float* mrow = mask + (size_t)o * IN_;

    int loc[4];
    int c = 0;
    int ibase = t * 4;
#pragma unroll
    for (int k = 0; k < 4; ++k) {
        if (mrow[ibase + k] != 0.0f) loc[c++] = ibase + k;
    }
    int v = c;
#pragma unroll
    for (int off = 1; off < 64; off <<= 1) {
        int u = __shfl_up(v, off, 64);
        if (lane >= off) v += u;
    }
    __shared__ int wsum[4];
    if (lane == 63) wsum[wv] = v;
    __syncthreads();
    int base = 0;
    for (int w = 0; w < wv; ++w) base += wsum[w];
    int excl = base + v - c;

    int* orow = idx + (size_t)o * IN_;
    for (int k = 0; k < c; ++k) orow[excl + k] = loc[k];
    if (t == 255) cnt[o] = base + v;
}

__global__ __launch_bounds__(256) void spmm_kernel(const float* __restrict__ xT,
                                                   const float* __restrict__ peso,
                                                   const int* __restrict__ cnt,
                                                   const int* __restrict__ idx,
                                                   float* __restrict__ out) {
    __shared__ int sidx[IN_];

    int bid  = blockIdx.x;
    int o    = bid & (OUT_ - 1);          // all 4 b-tiles of an o land on one XCD
    int bt   = bid >> 9;                  // 0..3
    int t    = threadIdx.x;
    int lane = t & 63;
    int wv   = __builtin_amdgcn_readfirstlane(t >> 6);
    int b0   = bt * 64 + wv * 16;         // this wave's 16 b rows

    int n = cnt[o];
    const int* irow = idx + (size_t)o * IN_;
    for (int f = t; f < n; f += 256) sidx[f] = irow[f];
    __syncthreads();

    float2 acc[16];
#pragma unroll
    for (int k = 0; k < 16; ++k) acc[k] = make_float2(0.0f, 0.0f);

    const float2* wlane = (const float2*)(peso + (size_t)o * IN_ * DS_) + lane;
    const float*  xb    = xT + b0;

    // depth-2 software pipeline
    int i_cur = (n > 0) ? __builtin_amdgcn_readfirstlane(sidx[0]) : 0;
    float2 w_cur = wlane[(size_t)i_cur * (DS_ / 2)];
    f16v  xs_cur = *(const f16v*)(xb + (size_t)i_cur * B_);

#pragma unroll 2
    for (int j = 0; j < n; ++j) {
        int jn = (j + 1 < n) ? j + 1 : j;
        int i_nxt = __builtin_amdgcn_readfirstlane(sidx[jn]);
        float2 w_nxt = wlane[(size_t)i_nxt * (DS_ / 2)];          // 512B/wave
        f16v  xs_nxt = *(const f16v*)(xb + (size_t)i_nxt * B_);   // uniform 64B

        float2 w = w_cur;
        f16v  xs = xs_cur;
#pragma unroll
        for (int k = 0; k < 16; ++k) {
            acc[k].x = fmaf(xs[k], w.x, acc[k].x);
            acc[k].y = fmaf(xs[k], w.y, acc[k].y);
        }
        w_cur = w_nxt;
        xs_cur = xs_nxt;
    }

    float* obase = out + (size_t)b0 * (OUT_ * DS_) + o * DS_ + 2 * lane;
#pragma unroll
    for (int k = 0; k < 16; ++k) {
        *(float2*)(obase + (size_t)k * (OUT_ * DS_)) = acc[k];  // 512B/wave contiguous
    }
}

extern "C" void kernel_launch(void* const* d_in, const int* in_sizes, int n_in,
                              void* d_out, int out_size, void* d_ws, size_t ws_size,
                              hipStream_t stream) {
    const float* x    = (const float*)d_in[0];
    const float* peso = (const float*)d_in[1];
    const float* mask = (const float*)d_in[2];
    float* out = (float*)d_out;

    char* ws = (char*)d_ws;
    float* xT  = (float*)ws;
    int*   cnt = (int*)(ws + (1 << 20));
    int*   idx = (int*)(ws + (1 << 20) + 4096);

    transpose_x<<<64, 256, 0, stream>>>(x, xT);
    build_idx<<<OUT_, 256, 0, stream>>>(mask, cnt, idx);
    spmm_kernel<<<OUT_ * 4, 256, 0, stream>>>(xT, peso, cnt, idx, out);
}